// Round 2
// baseline (369.541 us; speedup 1.0000x reference)
//
#include <hip/hip_runtime.h>
#include <stdint.h>

#define O_FEATS 28672
#define I_FEATS 8192
#define BATCH 8
#define WPR 2048   // packed int32 words per output row (I/4)

// ---------------------------------------------------------------------------
// Workspace layout (uint32 indices into ws):
//   ws[0]        : absmax bits (uint, non-negative float compares as uint)
//   ws[4..11]    : sum_x[8] (int32)  -- per-batch sum of quantized activations
//   ws[64..]     : x_q int8 [8][8192]  (byte offset 256, 16B-aligned)
// ---------------------------------------------------------------------------

#if __has_builtin(__builtin_amdgcn_sdot4)
#define DOT4(a, b, c) __builtin_amdgcn_sdot4((a), (b), (c), false)
#else
static __device__ __forceinline__ int dot4_sw(int a, int b, int c) {
  c += (int)(signed char)(a & 0xff) * (int)(signed char)(b & 0xff);
  c += (int)(signed char)((a >> 8) & 0xff) * (int)(signed char)((b >> 8) & 0xff);
  c += (int)(signed char)((a >> 16) & 0xff) * (int)(signed char)((b >> 16) & 0xff);
  c += (int)(signed char)((a >> 24) & 0xff) * (int)(signed char)((b >> 24) & 0xff);
  return c;
}
#define DOT4(a, b, c) dot4_sw((a), (b), (c))
#endif

// Carry-free unpack: packed word p has 4 ternary codes in bits [7:0]
// (c0|c1<<2|c2<<4|c3<<6). Produce bytes {c0,c1,c2,c3} (unsigned 0..2).
// lo=p&0xF holds c0,c1; lo*0x41 = lo | lo<<6 (no overlap: lo is 4 bits,
// shifted copy starts at bit 6) -> c0 at [1:0], c1 at [9:8]. Same for hi.
static __device__ __forceinline__ int unpack4(uint32_t p) {
  uint32_t lo = p & 0x0Fu;
  uint32_t hi = (p >> 4) & 0x0Fu;
  uint32_t a = (lo * 0x41u) & 0x0303u;
  uint32_t b = (hi * 0x41u) & 0x0303u;
  return (int)(a | (b << 16));
}

__global__ void k_init(uint32_t* __restrict__ ws) {
  int t = threadIdx.x;
  if (t == 0) ws[0] = 0u;
  if (t >= 4 && t < 12) ws[t] = 0u;
}

// 64 blocks x 256 threads x 4 floats = 65536 elements
__global__ void k_absmax(const float* __restrict__ x, uint32_t* __restrict__ ws) {
  int idx = blockIdx.x * 256 + threadIdx.x;
  float4 v = ((const float4*)x)[idx];
  float m = fmaxf(fmaxf(fabsf(v.x), fabsf(v.y)), fmaxf(fabsf(v.z), fabsf(v.w)));
#pragma unroll
  for (int off = 32; off; off >>= 1)
    m = fmaxf(m, __shfl_xor(m, off));
  if ((threadIdx.x & 63) == 0)
    atomicMax(ws, __float_as_uint(m));
}

// 64 blocks: block (b = blk>>3, seg = blk&7) quantizes 1024 elems of row b.
__global__ void k_quant(const float* __restrict__ x, uint32_t* __restrict__ ws) {
  int b = blockIdx.x >> 3, seg = blockIdx.x & 7;
  int t = threadIdx.x;
  float amax = fmaxf(__uint_as_float(ws[0]), 1e-5f);
  float s = amax / 127.0f;                 // match ref: x / (absmax/127)
  float4 v = ((const float4*)(x + b * I_FEATS + seg * 1024))[t];
  int q0 = (int)fminf(fmaxf(rintf(v.x / s), -128.f), 127.f);
  int q1 = (int)fminf(fmaxf(rintf(v.y / s), -128.f), 127.f);
  int q2 = (int)fminf(fmaxf(rintf(v.z / s), -128.f), 127.f);
  int q3 = (int)fminf(fmaxf(rintf(v.w / s), -128.f), 127.f);
  uint32_t pk = (uint32_t)(q0 & 0xff) | ((uint32_t)(q1 & 0xff) << 8) |
                ((uint32_t)(q2 & 0xff) << 16) | ((uint32_t)(q3 & 0xff) << 24);
  ws[64 + b * 2048 + seg * 256 + t] = pk;
  int s4 = q0 + q1 + q2 + q3;
#pragma unroll
  for (int off = 32; off; off >>= 1)
    s4 += __shfl_xor(s4, off);
  if ((t & 63) == 0)
    atomicAdd((int*)ws + 4 + b, s4);
}

// GEMM: 1792 blocks x 256 thr. Block -> 16 output rows; wave -> 4 rows.
// Lane l, iter j owns packed-word chunk c = j*64+l (16 weights = 16B).
__global__ void __launch_bounds__(256, 2)
k_gemm(const int* __restrict__ Wp, const float* __restrict__ wscale,
       const float* __restrict__ bias, const uint32_t* __restrict__ ws,
       float* __restrict__ out) {
  __shared__ uint32_t xq_lds[BATCH * 2048];  // 64 KB: x_q int8 [8][8192]

  int t = threadIdx.x;
  // stage x_q global(ws) -> LDS, 4096 int4 across 256 threads
  {
    const int4* src = (const int4*)(ws + 64);
    int4* dst = (int4*)xq_lds;
#pragma unroll
    for (int i = 0; i < 16; ++i) dst[t + 256 * i] = src[t + 256 * i];
  }
  __syncthreads();

  const int wave = t >> 6, lane = t & 63;
  const int o_base = blockIdx.x * 16 + wave * 4;

  int4 wcur[4], wnxt[4];
#pragma unroll
  for (int oo = 0; oo < 4; ++oo)
    wcur[oo] = *(const int4*)(Wp + (o_base + oo) * WPR + 4 * lane);

  int acc[4][8];
#pragma unroll
  for (int oo = 0; oo < 4; ++oo)
#pragma unroll
    for (int b = 0; b < 8; ++b) acc[oo][b] = 0;

#pragma unroll
  for (int j = 0; j < 8; ++j) {
    const int cc = j * 64 + lane;
    if (j < 7) {
#pragma unroll
      for (int oo = 0; oo < 4; ++oo)
        wnxt[oo] = *(const int4*)(Wp + (o_base + oo) * WPR + 4 * (cc + 64));
    }
    // unpack 2-bit codes -> 4 unsigned bytes per packed word (carry-free)
    int code[4][4];
#pragma unroll
    for (int oo = 0; oo < 4; ++oo) {
      const uint32_t* pw = (const uint32_t*)&wcur[oo];
#pragma unroll
      for (int m = 0; m < 4; ++m)
        code[oo][m] = unpack4(pw[m]);
    }
#pragma unroll
    for (int b = 0; b < 8; ++b) {
      int4 xv = *(const int4*)&xq_lds[b * 2048 + 4 * cc];
#pragma unroll
      for (int oo = 0; oo < 4; ++oo) {
        acc[oo][b] = DOT4(code[oo][0], xv.x, acc[oo][b]);
        acc[oo][b] = DOT4(code[oo][1], xv.y, acc[oo][b]);
        acc[oo][b] = DOT4(code[oo][2], xv.z, acc[oo][b]);
        acc[oo][b] = DOT4(code[oo][3], xv.w, acc[oo][b]);
      }
    }
#pragma unroll
    for (int oo = 0; oo < 4; ++oo) wcur[oo] = wnxt[oo];
  }

  // Split-butterfly reduction: 32 partials/lane summed across 64 lanes with
  // only 16+8+4+2+1+1 = 32 shuffles/lane. After 5 splitting steps lane L's
  // v[0] holds value index h = bitrev5(L&31), summed over its 32-lane group.
  int v[32];
#pragma unroll
  for (int oo = 0; oo < 4; ++oo)
#pragma unroll
    for (int b = 0; b < 8; ++b) v[oo * 8 + b] = acc[oo][b];
#pragma unroll
  for (int s = 0; s < 5; ++s) {
    const int m = 1 << s;
    const int n = 16 >> s;
    const bool up = (lane & m) != 0;
#pragma unroll
    for (int i = 0; i < n; ++i) {
      int give = up ? v[i] : v[i + n];
      int keep = up ? v[i + n] : v[i];
      v[i] = keep + __shfl_xor(give, m);
    }
  }
  int tot = v[0] + __shfl_xor(v[0], 32);

  if (lane < 32) {
    // h = bit-reverse of low 5 lane bits; value index = oo*8 + b
    int h = ((lane & 1) << 4) | ((lane & 2) << 2) | (lane & 4) |
            ((lane & 8) >> 2) | ((lane & 16) >> 4);
    int oo = h >> 3, b = h & 7;
    float amax = fmaxf(__uint_as_float(ws[0]), 1e-5f);
    float scale = (amax / 127.0f) * wscale[0];
    int sumx = ((const int*)ws)[4 + b];
    int o = o_base + oo;
    out[b * O_FEATS + o] = (float)(tot - sumx) * scale + bias[o];
  }
}

extern "C" void kernel_launch(void* const* d_in, const int* in_sizes, int n_in,
                              void* d_out, int out_size, void* d_ws, size_t ws_size,
                              hipStream_t stream) {
  const float* x = (const float*)d_in[0];
  const int* pw = (const int*)d_in[1];
  const float* wscale = (const float*)d_in[2];
  const float* bias = (const float*)d_in[3];
  float* out = (float*)d_out;
  uint32_t* ws = (uint32_t*)d_ws;

  k_init<<<1, 64, 0, stream>>>(ws);
  k_absmax<<<64, 256, 0, stream>>>(x, ws);
  k_quant<<<64, 256, 0, stream>>>(x, ws);
  k_gemm<<<1792, 256, 0, stream>>>(pw, wscale, bias, ws, out);
}